// Round 1
// 615.818 us; speedup vs baseline: 1.2785x; 1.2785x over previous
//
#include <hip/hip_runtime.h>
#include <hip/hip_bf16.h>
#include <type_traits>

#define NN 50000

typedef __attribute__((ext_vector_type(8))) short bf16x8;
typedef __attribute__((ext_vector_type(4))) float f32x4;

__device__ __forceinline__ ushort f2bf(float f) {
    unsigned u = __builtin_bit_cast(unsigned, f);
    unsigned r = (u + 0x7fffu + ((u >> 16) & 1u)) >> 16;  // RTN-even
    return (ushort)r;
}
__device__ __forceinline__ float bflo(unsigned v) { return __builtin_bit_cast(float, v << 16); }
__device__ __forceinline__ float bfhi(unsigned v) { return __builtin_bit_cast(float, v & 0xffff0000u); }

// ---------------------------------------------------------------------------
// edge_index dtype detection (int32 vs int64), on device (graph-safe).
__global__ void k_detect(const unsigned int* ei, int npairs, int* flag) {
    __shared__ int any_nz;
    if (threadIdx.x == 0) any_nz = 0;
    __syncthreads();
    for (int i = threadIdx.x; i < npairs; i += blockDim.x) {
        if (ei[2 * i + 1] != 0u) atomicOr(&any_nz, 1);
    }
    __syncthreads();
    if (threadIdx.x == 0) *flag = (any_nz == 0) ? 1 : 0;
}

__device__ __forceinline__ int load_idx(const void* ei, long long pos, int is64) {
    return is64 ? (int)(((const long long*)ei)[pos]) : ((const int*)ei)[pos];
}

__global__ void k_init(int* cnt, int* cur, int n) {
    int i = blockIdx.x * blockDim.x + threadIdx.x;
    if (i < n) { cnt[i] = 0; cur[i] = 0; }
}

__global__ void k_count(const void* ei, long long E, const int* flag, int* cnt) {
    long long e = (long long)blockIdx.x * blockDim.x + threadIdx.x;
    if (e < E) {
        int dst = load_idx(ei, E + e, *flag);
        atomicAdd(&cnt[dst], 1);
    }
}

// Single-block exclusive scan of cnt -> offs, plus dinv = rsqrt(cnt+1).
// Shuffle-based wave scan + 16-partial scan: 3 barriers per 1024-chunk
// (was 20 with the pure-LDS ladder).
__global__ void k_scan(const int* __restrict__ cnt, int* __restrict__ offs,
                       float* __restrict__ dinv, int n) {
    __shared__ int wsum[16];
    __shared__ int carry_s;
    int t = (int)threadIdx.x;
    int lane = t & 63, w = t >> 6;
    if (t == 0) carry_s = 0;
    __syncthreads();
    for (int base = 0; base < n; base += 1024) {
        int i = base + t;
        int v = (i < n) ? cnt[i] : 0;
        int x = v;
#pragma unroll
        for (int off = 1; off < 64; off <<= 1) {
            int y = __shfl_up(x, off);
            if (lane >= off) x += y;
        }
        if (lane == 63) wsum[w] = x;
        __syncthreads();
        if (w == 0) {
            int pv = (lane < 16) ? wsum[lane] : 0;
#pragma unroll
            for (int off = 1; off < 16; off <<= 1) {
                int py = __shfl_up(pv, off);
                if (lane >= off) pv += py;
            }
            if (lane < 16) wsum[lane] = pv;
        }
        __syncthreads();
        int wbase = (w > 0) ? wsum[w - 1] : 0;
        int incl = x + wbase;
        int excl = incl - v;
        int carry = carry_s;
        if (i < n) {
            offs[i] = carry + excl;
            dinv[i] = rsqrtf((float)(v + 1));  // +1: self loop
        }
        __syncthreads();
        if (t == 1023) carry_s = carry + incl;
        __syncthreads();
    }
    if (threadIdx.x == 0) offs[n] = carry_s;
}

__global__ void k_bucket(const void* ei, long long E, const int* __restrict__ flag,
                         const float* __restrict__ dinv, const int* __restrict__ offs,
                         int* cur, int2* __restrict__ epk) {
    long long e = (long long)blockIdx.x * blockDim.x + threadIdx.x;
    if (e < E) {
        int is64 = *flag;
        int src = load_idx(ei, e, is64);
        int dst = load_idx(ei, E + e, is64);
        int pos = offs[dst] + atomicAdd(&cur[dst], 1);
        epk[pos] = make_int2(src, __builtin_bit_cast(int, dinv[src] * dinv[dst]));
    }
}

// ---------------------------------------------------------------------------
// Weight transpose + cast: WT[n*K+k] = bf16(W[k*N+n])
__global__ void k_wt(const float* __restrict__ W, ushort* __restrict__ WT, int K, int N) {
    int id = blockIdx.x * 256 + threadIdx.x;
    if (id < K * N) {
        int nn = id / K, k = id - nn * K;
        WT[id] = f2bf(W[(long long)k * N + nn]);
    }
}

// ---------------------------------------------------------------------------
// bf16 MFMA GEMM: C[M,N] = A[M,K] * WT[N,K]^T, 128x128 tile, BK=64, 4 waves.
// LDS layout per tile: [128 rows][8 slots of 8 bf16], slot XOR-swizzled by row&7.
#define LOFF(r, s) (((r) * 8 + ((s) ^ ((r) & 7))) * 8)

template <typename TA>
__global__ __launch_bounds__(256) void k_gemm_mfma(const TA* __restrict__ A,
                                                   const ushort* __restrict__ WT,
                                                   ushort* __restrict__ C,
                                                   int M, int N, int K) {
    __shared__ ushort As[8192];
    __shared__ ushort Bs[8192];
    int t = threadIdx.x;
    int lane = t & 63;
    int w = t >> 6;
    int wr = (w >> 1) * 64, wc = (w & 1) * 64;
    int m0 = blockIdx.y * 128, n0 = blockIdx.x * 128;

    f32x4 acc[4][4] = {};

    for (int k0 = 0; k0 < K; k0 += 64) {
        // ---- stage A and B^T tiles (coalesced: 8 threads cover one 128B row) ----
#pragma unroll
        for (int j = 0; j < 4; ++j) {
            int id = t + j * 256;
            int r = id >> 3, s = id & 7;
            {   // B^T tile: rows are output columns (always in range)
                const ushort* src = WT + (long long)(n0 + r) * K + k0 + s * 8;
                *(uint4*)&Bs[LOFF(r, s)] = *(const uint4*)src;
            }
            int grow = m0 + r;
            if (grow < M) {
                if constexpr (std::is_same<TA, float>::value) {
                    const float* src = A + (long long)grow * K + k0 + s * 8;
                    float4 f0 = *(const float4*)src;
                    float4 f1 = *(const float4*)(src + 4);
                    ushort tmp[8] = {f2bf(f0.x), f2bf(f0.y), f2bf(f0.z), f2bf(f0.w),
                                     f2bf(f1.x), f2bf(f1.y), f2bf(f1.z), f2bf(f1.w)};
                    *(uint4*)&As[LOFF(r, s)] = *(uint4*)tmp;
                } else {
                    const ushort* src = (const ushort*)A + (long long)grow * K + k0 + s * 8;
                    *(uint4*)&As[LOFF(r, s)] = *(const uint4*)src;
                }
            }
        }
        __syncthreads();
        // ---- MFMA: each wave computes a 64x64 sub-tile (4x4 fragments) ----
#pragma unroll
        for (int kk = 0; kk < 2; ++kk) {
            int ks = kk * 4 + (lane >> 4);
            bf16x8 a[4], b[4];
#pragma unroll
            for (int m = 0; m < 4; ++m)
                a[m] = *(bf16x8*)&As[LOFF(wr + m * 16 + (lane & 15), ks)];
#pragma unroll
            for (int nn = 0; nn < 4; ++nn)
                b[nn] = *(bf16x8*)&Bs[LOFF(wc + nn * 16 + (lane & 15), ks)];
#pragma unroll
            for (int m = 0; m < 4; ++m)
#pragma unroll
                for (int nn = 0; nn < 4; ++nn)
                    acc[m][nn] = __builtin_amdgcn_mfma_f32_16x16x32_bf16(a[m], b[nn], acc[m][nn], 0, 0, 0);
        }
        __syncthreads();
    }
    // ---- epilogue: D frag (reg i): row=(lane>>4)*4+i, col=lane&15 (m89 layout) ----
#pragma unroll
    for (int m = 0; m < 4; ++m) {
#pragma unroll
        for (int i = 0; i < 4; ++i) {
            int row = m0 + wr + m * 16 + (lane >> 4) * 4 + i;
            if (row < M) {
#pragma unroll
                for (int nn = 0; nn < 4; ++nn) {
                    int col = n0 + wc + nn * 16 + (lane & 15);
                    C[(long long)row * N + col] = f2bf(acc[m][nn][i]);
                }
            }
        }
    }
}

// ---------------------------------------------------------------------------
// Aggregation over bf16 h: out[i,:] = bias + dinv[i]^2*h[i,:] + sum enorm*h[src,:]
// One WAVE per node (64 lanes cover the full row: 8B/lane for D=256, 4B/lane
// for D=128). Edge loop unrolled 8-wide: 8 epk loads then 8 independent row
// gathers in flight per iteration (the old version had exactly ONE dependent
// epk->gather chain in flight => latency-bound at VALUBusy 14%). Tail is
// handled branchlessly by clamping the index and zeroing the weight.
// Two waves (2 nodes) per block to stay under the workgroup/CU cap.
template <int D, bool RELU, bool OUTF32>
__global__ __launch_bounds__(128) void k_agg2(const ushort* __restrict__ h,
                                              const int* __restrict__ offs,
                                              const int2* __restrict__ epk,
                                              const float* __restrict__ dinv,
                                              const float* __restrict__ bias,
                                              void* __restrict__ outp, int n) {
    constexpr int VPT = D / 64;  // features per lane: 4 (D=256) or 2 (D=128)
    int node = blockIdx.x * 2 + (threadIdx.x >> 6);
    if (node >= n) return;
    int t = threadIdx.x & 63;
    float di = dinv[node];
    float dii = di * di;
    float acc[VPT];

    if constexpr (VPT == 4) {
        uint2 v = *(const uint2*)&h[(long long)node * D + t * 4];
        acc[0] = bias[4 * t + 0] + dii * bflo(v.x);
        acc[1] = bias[4 * t + 1] + dii * bfhi(v.x);
        acc[2] = bias[4 * t + 2] + dii * bflo(v.y);
        acc[3] = bias[4 * t + 3] + dii * bfhi(v.y);
    } else {
        unsigned v = *(const unsigned*)&h[(long long)node * D + t * 2];
        acc[0] = bias[2 * t + 0] + dii * bflo(v);
        acc[1] = bias[2 * t + 1] + dii * bfhi(v);
    }

    int s = offs[node], e = offs[node + 1];
    for (int j = s; j < e; j += 8) {
        int2 p[8];
#pragma unroll
        for (int u = 0; u < 8; ++u) {
            int jj = (j + u < e) ? (j + u) : (e - 1);  // always in-bounds
            p[u] = epk[jj];
            if (j + u >= e) p[u].y = 0;                // weight 0 for tail slots
        }
        if constexpr (VPT == 4) {
            uint2 v[8];
#pragma unroll
            for (int u = 0; u < 8; ++u)
                v[u] = *(const uint2*)&h[(long long)p[u].x * D + t * 4];
#pragma unroll
            for (int u = 0; u < 8; ++u) {
                float wgt = __builtin_bit_cast(float, p[u].y);
                acc[0] += wgt * bflo(v[u].x);
                acc[1] += wgt * bfhi(v[u].x);
                acc[2] += wgt * bflo(v[u].y);
                acc[3] += wgt * bfhi(v[u].y);
            }
        } else {
            unsigned v[8];
#pragma unroll
            for (int u = 0; u < 8; ++u)
                v[u] = *(const unsigned*)&h[(long long)p[u].x * D + t * 2];
#pragma unroll
            for (int u = 0; u < 8; ++u) {
                float wgt = __builtin_bit_cast(float, p[u].y);
                acc[0] += wgt * bflo(v[u]);
                acc[1] += wgt * bfhi(v[u]);
            }
        }
    }

    if (RELU) {
#pragma unroll
        for (int u = 0; u < VPT; ++u) acc[u] = fmaxf(acc[u], 0.f);
    }
    if constexpr (OUTF32) {
        if constexpr (VPT == 2) {
            ((float2*)outp)[(long long)node * (D / 2) + t] = make_float2(acc[0], acc[1]);
        } else {
            float4 o = make_float4(acc[0], acc[1], acc[2], acc[3]);
            ((float4*)outp)[(long long)node * (D / 4) + t] = o;
        }
    } else {
        if constexpr (VPT == 4) {
            uint2 pk;
            pk.x = (unsigned)f2bf(acc[0]) | ((unsigned)f2bf(acc[1]) << 16);
            pk.y = (unsigned)f2bf(acc[2]) | ((unsigned)f2bf(acc[3]) << 16);
            ((uint2*)outp)[(long long)node * (D / 4) + t] = pk;
        } else {
            unsigned pk = (unsigned)f2bf(acc[0]) | ((unsigned)f2bf(acc[1]) << 16);
            ((unsigned*)outp)[(long long)node * (D / 2) + t] = pk;
        }
    }
}

// ---------------------------------------------------------------------------
extern "C" void kernel_launch(void* const* d_in, const int* in_sizes, int n_in,
                              void* d_out, int out_size, void* d_ws, size_t ws_size,
                              hipStream_t stream) {
    const float* x  = (const float*)d_in[0];
    const void*  ei = d_in[1];
    const float* W0 = (const float*)d_in[2];
    const float* b0 = (const float*)d_in[3];
    const float* W1 = (const float*)d_in[4];
    const float* b1 = (const float*)d_in[5];
    const float* W2 = (const float*)d_in[6];
    const float* b2 = (const float*)d_in[7];
    float* out = (float*)d_out;

    const int n = NN;
    const long long E = (long long)in_sizes[1] / 2;

    char* ws = (char*)d_ws;
    int*    cnt  = (int*)(ws);
    int*    cur  = (int*)(ws + 256 * 1024);
    int*    offs = (int*)(ws + 512 * 1024);
    float*  dinv = (float*)(ws + 768 * 1024);
    int*    flag = (int*)(ws + 1000 * 1024);
    int2*   epk  = (int2*)(ws + 1024 * 1024);                 // E*8B <= 16MB
    ushort* WT0  = (ushort*)(ws + 17ll * 1024 * 1024);        // 256KB
    ushort* WT1  = (ushort*)(ws + 17ll * 1024 * 1024 + 512 * 1024);
    ushort* WT2  = (ushort*)(ws + 17ll * 1024 * 1024 + 768 * 1024);
    ushort* hA   = (ushort*)(ws + 18ll * 1024 * 1024);        // 25.6MB
    ushort* hB   = (ushort*)(ws + 44ll * 1024 * 1024);        // 25.6MB

    // --- graph preprocessing ---
    k_detect<<<1, 256, 0, stream>>>((const unsigned int*)ei, 4096, flag);
    k_init<<<(n + 255) / 256, 256, 0, stream>>>(cnt, cur, n);
    k_count<<<(int)((E + 255) / 256), 256, 0, stream>>>(ei, E, flag, cnt);
    k_scan<<<1, 1024, 0, stream>>>(cnt, offs, dinv, n);
    k_bucket<<<(int)((E + 255) / 256), 256, 0, stream>>>(ei, E, flag, dinv, offs, cur, epk);

    // --- weight transpose+cast (independent of graph work) ---
    k_wt<<<(512 * 256 + 255) / 256, 256, 0, stream>>>(W0, WT0, 512, 256);
    k_wt<<<(256 * 256 + 255) / 256, 256, 0, stream>>>(W1, WT1, 256, 256);
    k_wt<<<(256 * 128 + 255) / 256, 256, 0, stream>>>(W2, WT2, 256, 128);

    int mt = (n + 127) / 128;
    int nb2 = (n + 1) / 2;

    // --- layer 0: x[50000,512](f32) @ W0 -> bf16 h -> relu agg ---
    k_gemm_mfma<float><<<dim3(2, mt), 256, 0, stream>>>(x, WT0, hA, n, 256, 512);
    k_agg2<256, true, false><<<nb2, 128, 0, stream>>>(hA, offs, epk, dinv, b0, hB, n);

    // --- layer 1 ---
    k_gemm_mfma<ushort><<<dim3(2, mt), 256, 0, stream>>>(hB, WT1, hA, n, 256, 256);
    k_agg2<256, true, false><<<nb2, 128, 0, stream>>>(hA, offs, epk, dinv, b1, hB, n);

    // --- layer 2 (f32 output) ---
    k_gemm_mfma<ushort><<<dim3(1, mt), 256, 0, stream>>>(hB, WT2, hA, n, 128, 256);
    k_agg2<128, false, true><<<nb2, 128, 0, stream>>>(hA, offs, epk, dinv, b2, out, n);
}

// Round 2
// 576.940 us; speedup vs baseline: 1.3646x; 1.0674x over previous
//
#include <hip/hip_runtime.h>
#include <hip/hip_bf16.h>
#include <type_traits>

#define NN 50000

typedef __attribute__((ext_vector_type(8))) short bf16x8;
typedef __attribute__((ext_vector_type(4))) float f32x4;

__device__ __forceinline__ ushort f2bf(float f) {
    unsigned u = __builtin_bit_cast(unsigned, f);
    unsigned r = (u + 0x7fffu + ((u >> 16) & 1u)) >> 16;  // RTN-even
    return (ushort)r;
}
__device__ __forceinline__ float bflo(unsigned v) { return __builtin_bit_cast(float, v << 16); }
__device__ __forceinline__ float bfhi(unsigned v) { return __builtin_bit_cast(float, v & 0xffff0000u); }

// ---------------------------------------------------------------------------
// edge_index dtype detection (int32 vs int64), on device (graph-safe).
__global__ void k_detect(const unsigned int* ei, int npairs, int* flag) {
    __shared__ int any_nz;
    if (threadIdx.x == 0) any_nz = 0;
    __syncthreads();
    for (int i = threadIdx.x; i < npairs; i += blockDim.x) {
        if (ei[2 * i + 1] != 0u) atomicOr(&any_nz, 1);
    }
    __syncthreads();
    if (threadIdx.x == 0) *flag = (any_nz == 0) ? 1 : 0;
}

__device__ __forceinline__ int load_idx(const void* ei, long long pos, int is64) {
    return is64 ? (int)(((const long long*)ei)[pos]) : ((const int*)ei)[pos];
}

__global__ void k_init(int* cnt, int* cur, int n) {
    int i = blockIdx.x * blockDim.x + threadIdx.x;
    if (i < n) { cnt[i] = 0; cur[i] = 0; }
}

__global__ void k_count(const void* ei, long long E, const int* flag, int* cnt) {
    long long e = (long long)blockIdx.x * blockDim.x + threadIdx.x;
    if (e < E) {
        int dst = load_idx(ei, E + e, *flag);
        atomicAdd(&cnt[dst], 1);
    }
}

// Single-block exclusive scan of PADDED counts -> offs (each bucket rounded up
// to a multiple of 8 so the agg loop needs no tail handling and epk chunks are
// 64B-aligned for scalar loads), plus dinv = rsqrt(cnt+1).
__global__ void k_scan(const int* __restrict__ cnt, int* __restrict__ offs,
                       float* __restrict__ dinv, int n) {
    __shared__ int wsum[16];
    __shared__ int carry_s;
    int t = (int)threadIdx.x;
    int lane = t & 63, w = t >> 6;
    if (t == 0) carry_s = 0;
    __syncthreads();
    for (int base = 0; base < n; base += 1024) {
        int i = base + t;
        int v = (i < n) ? cnt[i] : 0;
        int pv = (v + 7) & ~7;  // padded bucket width
        int x = pv;
#pragma unroll
        for (int off = 1; off < 64; off <<= 1) {
            int y = __shfl_up(x, off);
            if (lane >= off) x += y;
        }
        if (lane == 63) wsum[w] = x;
        __syncthreads();
        if (w == 0) {
            int pvv = (lane < 16) ? wsum[lane] : 0;
#pragma unroll
            for (int off = 1; off < 16; off <<= 1) {
                int py = __shfl_up(pvv, off);
                if (lane >= off) pvv += py;
            }
            if (lane < 16) wsum[lane] = pvv;
        }
        __syncthreads();
        int wbase = (w > 0) ? wsum[w - 1] : 0;
        int incl = x + wbase;
        int excl = incl - pv;
        int carry = carry_s;
        if (i < n) {
            offs[i] = carry + excl;
            dinv[i] = rsqrtf((float)(v + 1));  // +1: self loop
        }
        __syncthreads();
        if (t == 1023) carry_s = carry + incl;
        __syncthreads();
    }
    if (threadIdx.x == 0) offs[n] = carry_s;
}

// Fill pad slots [offs[i]+cnt[i], offs[i+1]) with zero-weight edges (src=0).
__global__ void k_pad(const int* __restrict__ cnt, const int* __restrict__ offs,
                      int2* __restrict__ epk, int n) {
    int i = blockIdx.x * blockDim.x + threadIdx.x;
    if (i < n) {
        int b = offs[i] + cnt[i], e = offs[i + 1];
        for (int j = b; j < e; ++j) epk[j] = make_int2(0, 0);
    }
}

__global__ void k_bucket(const void* ei, long long E, const int* __restrict__ flag,
                         const float* __restrict__ dinv, const int* __restrict__ offs,
                         int* cur, int2* __restrict__ epk) {
    long long e = (long long)blockIdx.x * blockDim.x + threadIdx.x;
    if (e < E) {
        int is64 = *flag;
        int src = load_idx(ei, e, is64);
        int dst = load_idx(ei, E + e, is64);
        int pos = offs[dst] + atomicAdd(&cur[dst], 1);
        epk[pos] = make_int2(src, __builtin_bit_cast(int, dinv[src] * dinv[dst]));
    }
}

// ---------------------------------------------------------------------------
// Weight transpose + cast: WT[n*K+k] = bf16(W[k*N+n])
__global__ void k_wt(const float* __restrict__ W, ushort* __restrict__ WT, int K, int N) {
    int id = blockIdx.x * 256 + threadIdx.x;
    if (id < K * N) {
        int nn = id / K, k = id - nn * K;
        WT[id] = f2bf(W[(long long)k * N + nn]);
    }
}

// ---------------------------------------------------------------------------
// bf16 MFMA GEMM: C[M,N] = A[M,K] * WT[N,K]^T, 128x128 tile, BK=64, 4 waves.
// LDS layout per tile: [128 rows][8 slots of 8 bf16], slot XOR-swizzled by row&7.
#define LOFF(r, s) (((r) * 8 + ((s) ^ ((r) & 7))) * 8)

template <typename TA>
__global__ __launch_bounds__(256) void k_gemm_mfma(const TA* __restrict__ A,
                                                   const ushort* __restrict__ WT,
                                                   ushort* __restrict__ C,
                                                   int M, int N, int K) {
    __shared__ ushort As[8192];
    __shared__ ushort Bs[8192];
    int t = threadIdx.x;
    int lane = t & 63;
    int w = t >> 6;
    int wr = (w >> 1) * 64, wc = (w & 1) * 64;
    int m0 = blockIdx.y * 128, n0 = blockIdx.x * 128;

    f32x4 acc[4][4] = {};

    for (int k0 = 0; k0 < K; k0 += 64) {
        // ---- stage A and B^T tiles (coalesced: 8 threads cover one 128B row) ----
#pragma unroll
        for (int j = 0; j < 4; ++j) {
            int id = t + j * 256;
            int r = id >> 3, s = id & 7;
            {   // B^T tile: rows are output columns (always in range)
                const ushort* src = WT + (long long)(n0 + r) * K + k0 + s * 8;
                *(uint4*)&Bs[LOFF(r, s)] = *(const uint4*)src;
            }
            int grow = m0 + r;
            if (grow < M) {
                if constexpr (std::is_same<TA, float>::value) {
                    const float* src = A + (long long)grow * K + k0 + s * 8;
                    float4 f0 = *(const float4*)src;
                    float4 f1 = *(const float4*)(src + 4);
                    ushort tmp[8] = {f2bf(f0.x), f2bf(f0.y), f2bf(f0.z), f2bf(f0.w),
                                     f2bf(f1.x), f2bf(f1.y), f2bf(f1.z), f2bf(f1.w)};
                    *(uint4*)&As[LOFF(r, s)] = *(uint4*)tmp;
                } else {
                    const ushort* src = (const ushort*)A + (long long)grow * K + k0 + s * 8;
                    *(uint4*)&As[LOFF(r, s)] = *(const uint4*)src;
                }
            }
        }
        __syncthreads();
        // ---- MFMA: each wave computes a 64x64 sub-tile (4x4 fragments) ----
#pragma unroll
        for (int kk = 0; kk < 2; ++kk) {
            int ks = kk * 4 + (lane >> 4);
            bf16x8 a[4], b[4];
#pragma unroll
            for (int m = 0; m < 4; ++m)
                a[m] = *(bf16x8*)&As[LOFF(wr + m * 16 + (lane & 15), ks)];
#pragma unroll
            for (int nn = 0; nn < 4; ++nn)
                b[nn] = *(bf16x8*)&Bs[LOFF(wc + nn * 16 + (lane & 15), ks)];
#pragma unroll
            for (int m = 0; m < 4; ++m)
#pragma unroll
                for (int nn = 0; nn < 4; ++nn)
                    acc[m][nn] = __builtin_amdgcn_mfma_f32_16x16x32_bf16(a[m], b[nn], acc[m][nn], 0, 0, 0);
        }
        __syncthreads();
    }
    // ---- epilogue: D frag (reg i): row=(lane>>4)*4+i, col=lane&15 (m89 layout) ----
#pragma unroll
    for (int m = 0; m < 4; ++m) {
#pragma unroll
        for (int i = 0; i < 4; ++i) {
            int row = m0 + wr + m * 16 + (lane >> 4) * 4 + i;
            if (row < M) {
#pragma unroll
                for (int nn = 0; nn < 4; ++nn) {
                    int col = n0 + wc + nn * 16 + (lane & 15);
                    C[(long long)row * N + col] = f2bf(acc[m][nn][i]);
                }
            }
        }
    }
}

// ---------------------------------------------------------------------------
// Aggregation over bf16 h: out[i,:] = bias + dinv[i]^2*h[i,:] + sum enorm*h[src,:]
// One WAVE per node. All wave-uniform work forced scalar via readfirstlane:
//  - epk chunks are 64B-aligned (buckets padded to x8) -> s_load_dwordx16
//  - gather base h + src*rowbytes computed on SALU, weight lives in SGPR
//  - zero per-gather VALU address math; no tail clamps (padding has w=0)
// 2-stage pipeline on the epk chunk hides the scalar-load latency.
template <int D, bool RELU, bool OUTF32>
__global__ __launch_bounds__(128) void k_agg2(const ushort* __restrict__ h,
                                              const int* __restrict__ offs,
                                              const int2* __restrict__ epk,
                                              const float* __restrict__ dinv,
                                              const float* __restrict__ bias,
                                              void* __restrict__ outp, int n) {
    constexpr int VPT = D / 64;  // features per lane: 4 (D=256) or 2 (D=128)
    int node = __builtin_amdgcn_readfirstlane((int)(blockIdx.x * 2 + (threadIdx.x >> 6)));
    if (node >= n) return;
    int t = (int)threadIdx.x & 63;
    float di = dinv[node];
    float dii = di * di;
    float acc[VPT];

    if constexpr (VPT == 4) {
        uint2 v = *(const uint2*)&h[(long long)node * D + t * 4];
        float4 bs = *(const float4*)&bias[t * 4];
        acc[0] = bs.x + dii * bflo(v.x);
        acc[1] = bs.y + dii * bfhi(v.x);
        acc[2] = bs.z + dii * bflo(v.y);
        acc[3] = bs.w + dii * bfhi(v.y);
    } else {
        unsigned v = *(const unsigned*)&h[(long long)node * D + t * 2];
        float2 bs = *(const float2*)&bias[t * 2];
        acc[0] = bs.x + dii * bflo(v);
        acc[1] = bs.y + dii * bfhi(v);
    }

    int s = offs[node], e = offs[node + 1];  // uniform -> scalar loads

    int2 pc[8], pn[8];
    if (s < e) {
#pragma unroll
        for (int u = 0; u < 8; ++u) pc[u] = epk[s + u];
    }
    for (int j = s; j < e; j += 8) {
        int jn = j + 8;
        if (jn < e) {
#pragma unroll
            for (int u = 0; u < 8; ++u) pn[u] = epk[jn + u];
        }
        if constexpr (VPT == 4) {
            uint2 v[8];
#pragma unroll
            for (int u = 0; u < 8; ++u)
                v[u] = *(const uint2*)&h[(long long)pc[u].x * D + t * 4];
#pragma unroll
            for (int u = 0; u < 8; ++u) {
                float wgt = __builtin_bit_cast(float, pc[u].y);
                acc[0] += wgt * bflo(v[u].x);
                acc[1] += wgt * bfhi(v[u].x);
                acc[2] += wgt * bflo(v[u].y);
                acc[3] += wgt * bfhi(v[u].y);
            }
        } else {
            unsigned v[8];
#pragma unroll
            for (int u = 0; u < 8; ++u)
                v[u] = *(const unsigned*)&h[(long long)pc[u].x * D + t * 2];
#pragma unroll
            for (int u = 0; u < 8; ++u) {
                float wgt = __builtin_bit_cast(float, pc[u].y);
                acc[0] += wgt * bflo(v[u]);
                acc[1] += wgt * bfhi(v[u]);
            }
        }
#pragma unroll
        for (int u = 0; u < 8; ++u) pc[u] = pn[u];
    }

    if (RELU) {
#pragma unroll
        for (int u = 0; u < VPT; ++u) acc[u] = fmaxf(acc[u], 0.f);
    }
    if constexpr (OUTF32) {
        if constexpr (VPT == 2) {
            ((float2*)outp)[(long long)node * (D / 2) + t] = make_float2(acc[0], acc[1]);
        } else {
            float4 o = make_float4(acc[0], acc[1], acc[2], acc[3]);
            ((float4*)outp)[(long long)node * (D / 4) + t] = o;
        }
    } else {
        if constexpr (VPT == 4) {
            uint2 pk;
            pk.x = (unsigned)f2bf(acc[0]) | ((unsigned)f2bf(acc[1]) << 16);
            pk.y = (unsigned)f2bf(acc[2]) | ((unsigned)f2bf(acc[3]) << 16);
            ((uint2*)outp)[(long long)node * (D / 4) + t] = pk;
        } else {
            unsigned pk = (unsigned)f2bf(acc[0]) | ((unsigned)f2bf(acc[1]) << 16);
            ((unsigned*)outp)[(long long)node * (D / 2) + t] = pk;
        }
    }
}

// ---------------------------------------------------------------------------
extern "C" void kernel_launch(void* const* d_in, const int* in_sizes, int n_in,
                              void* d_out, int out_size, void* d_ws, size_t ws_size,
                              hipStream_t stream) {
    const float* x  = (const float*)d_in[0];
    const void*  ei = d_in[1];
    const float* W0 = (const float*)d_in[2];
    const float* b0 = (const float*)d_in[3];
    const float* W1 = (const float*)d_in[4];
    const float* b1 = (const float*)d_in[5];
    const float* W2 = (const float*)d_in[6];
    const float* b2 = (const float*)d_in[7];
    float* out = (float*)d_out;

    const int n = NN;
    const long long E = (long long)in_sizes[1] / 2;

    char* ws = (char*)d_ws;
    int*    cnt  = (int*)(ws);
    int*    cur  = (int*)(ws + 256 * 1024);
    int*    offs = (int*)(ws + 512 * 1024);
    float*  dinv = (float*)(ws + 768 * 1024);
    int*    flag = (int*)(ws + 1000 * 1024);
    int2*   epk  = (int2*)(ws + 1024 * 1024);                 // (E + 7n)*8B <= 16MB
    ushort* WT0  = (ushort*)(ws + 17ll * 1024 * 1024);        // 256KB
    ushort* WT1  = (ushort*)(ws + 17ll * 1024 * 1024 + 512 * 1024);
    ushort* WT2  = (ushort*)(ws + 17ll * 1024 * 1024 + 768 * 1024);
    ushort* hA   = (ushort*)(ws + 18ll * 1024 * 1024);        // 25.6MB
    ushort* hB   = (ushort*)(ws + 44ll * 1024 * 1024);        // 25.6MB

    // --- graph preprocessing ---
    k_detect<<<1, 256, 0, stream>>>((const unsigned int*)ei, 4096, flag);
    k_init<<<(n + 255) / 256, 256, 0, stream>>>(cnt, cur, n);
    k_count<<<(int)((E + 255) / 256), 256, 0, stream>>>(ei, E, flag, cnt);
    k_scan<<<1, 1024, 0, stream>>>(cnt, offs, dinv, n);
    k_pad<<<(n + 255) / 256, 256, 0, stream>>>(cnt, offs, epk, n);
    k_bucket<<<(int)((E + 255) / 256), 256, 0, stream>>>(ei, E, flag, dinv, offs, cur, epk);

    // --- weight transpose+cast (independent of graph work) ---
    k_wt<<<(512 * 256 + 255) / 256, 256, 0, stream>>>(W0, WT0, 512, 256);
    k_wt<<<(256 * 256 + 255) / 256, 256, 0, stream>>>(W1, WT1, 256, 256);
    k_wt<<<(256 * 128 + 255) / 256, 256, 0, stream>>>(W2, WT2, 256, 128);

    int mt = (n + 127) / 128;
    int nb2 = (n + 1) / 2;

    // --- layer 0: x[50000,512](f32) @ W0 -> bf16 h -> relu agg ---
    k_gemm_mfma<float><<<dim3(2, mt), 256, 0, stream>>>(x, WT0, hA, n, 256, 512);
    k_agg2<256, true, false><<<nb2, 128, 0, stream>>>(hA, offs, epk, dinv, b0, hB, n);

    // --- layer 1 ---
    k_gemm_mfma<ushort><<<dim3(2, mt), 256, 0, stream>>>(hB, WT1, hA, n, 256, 256);
    k_agg2<256, true, false><<<nb2, 128, 0, stream>>>(hA, offs, epk, dinv, b1, hB, n);

    // --- layer 2 (f32 output) ---
    k_gemm_mfma<ushort><<<dim3(1, mt), 256, 0, stream>>>(hB, WT2, hA, n, 128, 256);
    k_agg2<128, false, true><<<nb2, 128, 0, stream>>>(hA, offs, epk, dinv, b2, out, n);
}